// Round 1
// baseline (259.813 us; speedup 1.0000x reference)
//
#include <hip/hip_runtime.h>

#define B_ 2
#define S_ 2048
#define F_ 1024
#define H_ 16
#define D_ 64

typedef __bf16 bf16x8 __attribute__((ext_vector_type(8)));
typedef float f32x4 __attribute__((ext_vector_type(4)));

__device__ __forceinline__ unsigned short f2bf(float f) {
    union { float f; unsigned int u; } v;
    v.f = f;
    unsigned int r = v.u + 0x7fffu + ((v.u >> 16) & 1u);
    return (unsigned short)(r >> 16);
}

// ---------- f32 -> bf16 elementwise convert (vectorized) ----------
__global__ void cvt_kernel(const float* __restrict__ in, unsigned short* __restrict__ out, int n4) {
    int i = blockIdx.x * blockDim.x + threadIdx.x;
    if (i >= n4) return;
    float4 v = reinterpret_cast<const float4*>(in)[i];
    ushort4 o;
    o.x = f2bf(v.x); o.y = f2bf(v.y); o.z = f2bf(v.z); o.w = f2bf(v.w);
    reinterpret_cast<ushort4*>(out)[i] = o;
}

// ---------- f32 [R][C] -> bf16 [C][R] transpose-convert ----------
__global__ void tcvt_kernel(const float* __restrict__ in, unsigned short* __restrict__ out, int R, int C) {
    __shared__ float t[32][33];
    int r0 = blockIdx.y << 5, c0 = blockIdx.x << 5;
    int tx = threadIdx.x, ty = threadIdx.y;
#pragma unroll
    for (int kk = 0; kk < 4; ++kk)
        t[ty + 8 * kk][tx] = in[(size_t)(r0 + ty + 8 * kk) * C + c0 + tx];
    __syncthreads();
#pragma unroll
    for (int kk = 0; kk < 4; ++kk)
        out[(size_t)(c0 + ty + 8 * kk) * R + r0 + tx] = f2bf(t[tx][ty + 8 * kk]);
}

// ---------- GEMM1: qkv = x @ w_attn + b_attn, scatter to q/k/v [B,H,S,D], q*=1/8 ----------
// A [4096][1024] bf16 row-major, Bt [3072][1024] bf16 (w_attn transposed)
__global__ __launch_bounds__(256) void gemm_qkv(const unsigned short* __restrict__ A,
                                                const unsigned short* __restrict__ Bt,
                                                const float* __restrict__ bias,
                                                unsigned short* __restrict__ qo,
                                                unsigned short* __restrict__ ko,
                                                unsigned short* __restrict__ vo) {
    __shared__ __align__(16) unsigned short As[128][40];
    __shared__ __align__(16) unsigned short Bs[128][40];
    const int K = 1024;
    int m0 = blockIdx.y << 7, n0 = blockIdx.x << 7;
    int tid = threadIdx.x;
    int w = tid >> 6, l = tid & 63, lg = l >> 4, lr = l & 15;
    int wm = (w >> 1) << 6, wn = (w & 1) << 6;
    f32x4 acc[4][4] = {};
    int ar = tid >> 2, ac = (tid & 3) << 3;

    for (int kt = 0; kt < K; kt += 32) {
        __syncthreads();
#pragma unroll
        for (int it = 0; it < 2; ++it) {
            int r = ar + (it << 6), c = ac;
            *reinterpret_cast<uint4*>(&As[r][c]) =
                *reinterpret_cast<const uint4*>(&A[(size_t)(m0 + r) * K + kt + c]);
            *reinterpret_cast<uint4*>(&Bs[r][c]) =
                *reinterpret_cast<const uint4*>(&Bt[(size_t)(n0 + r) * K + kt + c]);
        }
        __syncthreads();
        bf16x8 af[4], bfr[4];
#pragma unroll
        for (int mi = 0; mi < 4; ++mi)
            af[mi] = *reinterpret_cast<const bf16x8*>(&As[wm + mi * 16 + lr][lg << 3]);
#pragma unroll
        for (int ni = 0; ni < 4; ++ni)
            bfr[ni] = *reinterpret_cast<const bf16x8*>(&Bs[wn + ni * 16 + lr][lg << 3]);
#pragma unroll
        for (int mi = 0; mi < 4; ++mi)
#pragma unroll
            for (int ni = 0; ni < 4; ++ni)
                acc[mi][ni] = __builtin_amdgcn_mfma_f32_16x16x32_bf16(af[mi], bfr[ni], acc[mi][ni], 0, 0, 0);
    }
#pragma unroll
    for (int mi = 0; mi < 4; ++mi) {
#pragma unroll
        for (int ni = 0; ni < 4; ++ni) {
            int col = n0 + wn + ni * 16 + lr;
            float bv = bias[col];
            int part = col >> 10, cc = col & 1023, h = cc >> 6, d = cc & 63;
            unsigned short* dst = part == 0 ? qo : (part == 1 ? ko : vo);
            float scale = part == 0 ? 0.125f : 1.0f;
#pragma unroll
            for (int r = 0; r < 4; ++r) {
                int row = m0 + wm + mi * 16 + (lg << 2) + r;
                int bb = row >> 11, s = row & 2047;
                float vv = (acc[mi][ni][r] + bv) * scale;
                dst[(((size_t)bb * H_ + h) * S_ + s) * D_ + d] = f2bf(vv);
            }
        }
    }
}

// ---------- GEMM2: out = z @ w_proj + b_proj (f32 out) ----------
__global__ __launch_bounds__(256) void gemm_proj(const unsigned short* __restrict__ A,
                                                 const unsigned short* __restrict__ Bt,
                                                 const float* __restrict__ bias,
                                                 float* __restrict__ out) {
    __shared__ __align__(16) unsigned short As[128][40];
    __shared__ __align__(16) unsigned short Bs[128][40];
    const int K = 1024;
    int m0 = blockIdx.y << 7, n0 = blockIdx.x << 7;
    int tid = threadIdx.x;
    int w = tid >> 6, l = tid & 63, lg = l >> 4, lr = l & 15;
    int wm = (w >> 1) << 6, wn = (w & 1) << 6;
    f32x4 acc[4][4] = {};
    int ar = tid >> 2, ac = (tid & 3) << 3;

    for (int kt = 0; kt < K; kt += 32) {
        __syncthreads();
#pragma unroll
        for (int it = 0; it < 2; ++it) {
            int r = ar + (it << 6), c = ac;
            *reinterpret_cast<uint4*>(&As[r][c]) =
                *reinterpret_cast<const uint4*>(&A[(size_t)(m0 + r) * K + kt + c]);
            *reinterpret_cast<uint4*>(&Bs[r][c]) =
                *reinterpret_cast<const uint4*>(&Bt[(size_t)(n0 + r) * K + kt + c]);
        }
        __syncthreads();
        bf16x8 af[4], bfr[4];
#pragma unroll
        for (int mi = 0; mi < 4; ++mi)
            af[mi] = *reinterpret_cast<const bf16x8*>(&As[wm + mi * 16 + lr][lg << 3]);
#pragma unroll
        for (int ni = 0; ni < 4; ++ni)
            bfr[ni] = *reinterpret_cast<const bf16x8*>(&Bs[wn + ni * 16 + lr][lg << 3]);
#pragma unroll
        for (int mi = 0; mi < 4; ++mi)
#pragma unroll
            for (int ni = 0; ni < 4; ++ni)
                acc[mi][ni] = __builtin_amdgcn_mfma_f32_16x16x32_bf16(af[mi], bfr[ni], acc[mi][ni], 0, 0, 0);
    }
#pragma unroll
    for (int mi = 0; mi < 4; ++mi) {
#pragma unroll
        for (int ni = 0; ni < 4; ++ni) {
            int col = n0 + wn + ni * 16 + lr;
            float bv = bias[col];
#pragma unroll
            for (int r = 0; r < 4; ++r) {
                int row = m0 + wm + mi * 16 + (lg << 2) + r;
                out[(size_t)row * F_ + col] = acc[mi][ni][r] + bv;
            }
        }
    }
}

// ---------- causal flash attention ----------
// q,k,v: [B,H,S,D] bf16 (q pre-scaled).  z: [B,S,H*D] bf16
__global__ __launch_bounds__(256) void attn_kernel(const unsigned short* __restrict__ q,
                                                   const unsigned short* __restrict__ k,
                                                   const unsigned short* __restrict__ v,
                                                   unsigned short* __restrict__ z) {
    __shared__ __align__(16) unsigned short Ks[64][88];
    __shared__ __align__(16) unsigned short Vt[64][88];
    __shared__ __align__(16) unsigned short Pl[4][16][88];
    int qt = blockIdx.x, bh = blockIdx.y;
    int q0 = qt << 6;
    int tid = threadIdx.x, w = tid >> 6, l = tid & 63, lg = l >> 4, lr = l & 15;
    int q0w = q0 + (w << 4);
    size_t base = (size_t)bh * S_ * D_;

    bf16x8 qf[2];
#pragma unroll
    for (int c = 0; c < 2; ++c)
        qf[c] = *reinterpret_cast<const bf16x8*>(&q[base + (size_t)(q0w + lr) * D_ + (lg << 3) + 32 * c]);

    float m[4], lsum[4];
    f32x4 o[4] = {};
#pragma unroll
    for (int r = 0; r < 4; ++r) { m[r] = -1e30f; lsum[r] = 0.f; }

    int sr = tid >> 3, sc = (tid & 7) << 3;
    int ntiles = qt + 1;
    for (int jt = 0; jt < ntiles; ++jt) {
        int j = jt << 6;
        __syncthreads();
#pragma unroll
        for (int it = 0; it < 2; ++it) {
            int r = sr + (it << 5), c = sc;
            *reinterpret_cast<uint4*>(&Ks[r][c]) =
                *reinterpret_cast<const uint4*>(&k[base + (size_t)(j + r) * D_ + c]);
            uint4 vv = *reinterpret_cast<const uint4*>(&v[base + (size_t)(j + r) * D_ + c]);
            const unsigned short* vs = reinterpret_cast<const unsigned short*>(&vv);
#pragma unroll
            for (int i = 0; i < 8; ++i) Vt[c + i][r] = vs[i];
        }
        __syncthreads();

        f32x4 s[4] = {};
#pragma unroll
        for (int nt = 0; nt < 4; ++nt)
#pragma unroll
            for (int c = 0; c < 2; ++c) {
                bf16x8 kf = *reinterpret_cast<const bf16x8*>(&Ks[nt * 16 + lr][(lg << 3) + 32 * c]);
                s[nt] = __builtin_amdgcn_mfma_f32_16x16x32_bf16(qf[c], kf, s[nt], 0, 0, 0);
            }

        float pm[4];
#pragma unroll
        for (int r = 0; r < 4; ++r) pm[r] = -1e30f;
#pragma unroll
        for (int nt = 0; nt < 4; ++nt) {
            int col = j + nt * 16 + lr;
#pragma unroll
            for (int r = 0; r < 4; ++r) {
                int qrow = q0w + (lg << 2) + r;
                if (col > qrow) s[nt][r] = -1e30f;
                pm[r] = fmaxf(pm[r], s[nt][r]);
            }
        }
#pragma unroll
        for (int off = 1; off < 16; off <<= 1)
#pragma unroll
            for (int r = 0; r < 4; ++r) pm[r] = fmaxf(pm[r], __shfl_xor(pm[r], off));

        float ps[4], scl[4];
#pragma unroll
        for (int r = 0; r < 4; ++r) {
            float mn = fmaxf(m[r], pm[r]);
            scl[r] = __expf(m[r] - mn);
            m[r] = mn;
            ps[r] = 0.f;
        }
#pragma unroll
        for (int nt = 0; nt < 4; ++nt)
#pragma unroll
            for (int r = 0; r < 4; ++r) {
                float p = __expf(s[nt][r] - m[r]);
                ps[r] += p;
                Pl[w][(lg << 2) + r][nt * 16 + lr] = f2bf(p);
            }
#pragma unroll
        for (int off = 1; off < 16; off <<= 1)
#pragma unroll
            for (int r = 0; r < 4; ++r) ps[r] += __shfl_xor(ps[r], off);
#pragma unroll
        for (int r = 0; r < 4; ++r) lsum[r] = lsum[r] * scl[r] + ps[r];
#pragma unroll
        for (int dt = 0; dt < 4; ++dt)
#pragma unroll
            for (int r = 0; r < 4; ++r) o[dt][r] *= scl[r];

        bf16x8 pa[2];
#pragma unroll
        for (int c = 0; c < 2; ++c)
            pa[c] = *reinterpret_cast<const bf16x8*>(&Pl[w][lr][(lg << 3) + 32 * c]);
#pragma unroll
        for (int dt = 0; dt < 4; ++dt)
#pragma unroll
            for (int c = 0; c < 2; ++c) {
                bf16x8 vf = *reinterpret_cast<const bf16x8*>(&Vt[dt * 16 + lr][(lg << 3) + 32 * c]);
                o[dt] = __builtin_amdgcn_mfma_f32_16x16x32_bf16(pa[c], vf, o[dt], 0, 0, 0);
            }
    }

    int b = bh >> 4, h = bh & 15;
#pragma unroll
    for (int dt = 0; dt < 4; ++dt)
#pragma unroll
        for (int r = 0; r < 4; ++r) {
            int qrow = q0w + (lg << 2) + r;
            float val = o[dt][r] / lsum[r];
            z[((size_t)(b * S_ + qrow)) * F_ + h * D_ + dt * 16 + lr] = f2bf(val);
        }
}

extern "C" void kernel_launch(void* const* d_in, const int* in_sizes, int n_in,
                              void* d_out, int out_size, void* d_ws, size_t ws_size,
                              hipStream_t stream) {
    const float* x      = (const float*)d_in[0];
    const float* w_attn = (const float*)d_in[1];
    const float* b_attn = (const float*)d_in[2];
    const float* w_proj = (const float*)d_in[3];
    const float* b_proj = (const float*)d_in[4];
    float* out = (float*)d_out;
    char* ws = (char*)d_ws;

    unsigned short* xb   = (unsigned short*)(ws);              // [4096][1024] bf16, reused as z
    unsigned short* wa_t = (unsigned short*)(ws + 8388608);    // [3072][1024]
    unsigned short* wp_t = (unsigned short*)(ws + 14680064);   // [1024][1024]
    unsigned short* qb   = (unsigned short*)(ws + 16777216);   // [B,H,S,D]
    unsigned short* kb   = (unsigned short*)(ws + 25165824);
    unsigned short* vb   = (unsigned short*)(ws + 33554432);
    unsigned short* zb   = xb;                                 // alias: x consumed by gemm_qkv

    cvt_kernel<<<4096, 256, 0, stream>>>(x, xb, (4096 * 1024) / 4);
    tcvt_kernel<<<dim3(96, 32), dim3(32, 8), 0, stream>>>(w_attn, wa_t, 1024, 3072);
    tcvt_kernel<<<dim3(32, 32), dim3(32, 8), 0, stream>>>(w_proj, wp_t, 1024, 1024);
    gemm_qkv<<<dim3(24, 32), 256, 0, stream>>>(xb, wa_t, b_attn, qb, kb, vb);
    attn_kernel<<<dim3(32, 32), 256, 0, stream>>>(qb, kb, vb, zb);
    gemm_proj<<<dim3(8, 32), 256, 0, stream>>>(zb, wp_t, b_proj, out);
}

// Round 2
// 242.849 us; speedup vs baseline: 1.0699x; 1.0699x over previous
//
#include <hip/hip_runtime.h>

#define B_ 2
#define S_ 2048
#define F_ 1024
#define H_ 16
#define D_ 64

typedef __bf16 bf16x8 __attribute__((ext_vector_type(8)));
typedef float f32x4 __attribute__((ext_vector_type(4)));

__device__ __forceinline__ unsigned short f2bf(float f) {
    union { float f; unsigned int u; } v;
    v.f = f;
    unsigned int r = v.u + 0x7fffu + ((v.u >> 16) & 1u);
    return (unsigned short)(r >> 16);
}

// ---------- f32 -> bf16 elementwise convert (vectorized) ----------
__global__ void cvt_kernel(const float* __restrict__ in, unsigned short* __restrict__ out, int n4) {
    int i = blockIdx.x * blockDim.x + threadIdx.x;
    if (i >= n4) return;
    float4 v = reinterpret_cast<const float4*>(in)[i];
    ushort4 o;
    o.x = f2bf(v.x); o.y = f2bf(v.y); o.z = f2bf(v.z); o.w = f2bf(v.w);
    reinterpret_cast<ushort4*>(out)[i] = o;
}

// ---------- f32 [R][C] -> bf16 [C][R] transpose-convert ----------
__global__ void tcvt_kernel(const float* __restrict__ in, unsigned short* __restrict__ out, int R, int C) {
    __shared__ float t[32][33];
    int r0 = blockIdx.y << 5, c0 = blockIdx.x << 5;
    int tx = threadIdx.x, ty = threadIdx.y;
#pragma unroll
    for (int kk = 0; kk < 4; ++kk)
        t[ty + 8 * kk][tx] = in[(size_t)(r0 + ty + 8 * kk) * C + c0 + tx];
    __syncthreads();
#pragma unroll
    for (int kk = 0; kk < 4; ++kk)
        out[(size_t)(c0 + ty + 8 * kk) * R + r0 + tx] = f2bf(t[tx][ty + 8 * kk]);
}

// ---------- GEMM1: qkv = x @ w_attn + b_attn; q,k -> [B,H,S,D]; v -> [B,H,D,S] (transposed); q*=1/8 ----------
__global__ __launch_bounds__(256) void gemm_qkv(const unsigned short* __restrict__ A,
                                                const unsigned short* __restrict__ Bt,
                                                const float* __restrict__ bias,
                                                unsigned short* __restrict__ qo,
                                                unsigned short* __restrict__ ko,
                                                unsigned short* __restrict__ vo) {
    __shared__ __align__(16) unsigned short As[128][40];
    __shared__ __align__(16) unsigned short Bs[128][40];
    const int K = 1024;
    int m0 = blockIdx.y << 7, n0 = blockIdx.x << 7;
    int tid = threadIdx.x;
    int w = tid >> 6, l = tid & 63, lg = l >> 4, lr = l & 15;
    int wm = (w >> 1) << 6, wn = (w & 1) << 6;
    f32x4 acc[4][4] = {};
    int ar = tid >> 2, ac = (tid & 3) << 3;

    for (int kt = 0; kt < K; kt += 32) {
        __syncthreads();
#pragma unroll
        for (int it = 0; it < 2; ++it) {
            int r = ar + (it << 6), c = ac;
            *reinterpret_cast<uint4*>(&As[r][c]) =
                *reinterpret_cast<const uint4*>(&A[(size_t)(m0 + r) * K + kt + c]);
            *reinterpret_cast<uint4*>(&Bs[r][c]) =
                *reinterpret_cast<const uint4*>(&Bt[(size_t)(n0 + r) * K + kt + c]);
        }
        __syncthreads();
        bf16x8 af[4], bfr[4];
#pragma unroll
        for (int mi = 0; mi < 4; ++mi)
            af[mi] = *reinterpret_cast<const bf16x8*>(&As[wm + mi * 16 + lr][lg << 3]);
#pragma unroll
        for (int ni = 0; ni < 4; ++ni)
            bfr[ni] = *reinterpret_cast<const bf16x8*>(&Bs[wn + ni * 16 + lr][lg << 3]);
#pragma unroll
        for (int mi = 0; mi < 4; ++mi)
#pragma unroll
            for (int ni = 0; ni < 4; ++ni)
                acc[mi][ni] = __builtin_amdgcn_mfma_f32_16x16x32_bf16(af[mi], bfr[ni], acc[mi][ni], 0, 0, 0);
    }
#pragma unroll
    for (int mi = 0; mi < 4; ++mi) {
#pragma unroll
        for (int ni = 0; ni < 4; ++ni) {
            int col = n0 + wn + ni * 16 + lr;
            float bv = bias[col];
            int part = col >> 10, cc = col & 1023, h = cc >> 6, d = cc & 63;
            int row0 = m0 + wm + mi * 16 + (lg << 2);
            int bb = row0 >> 11, s0 = row0 & 2047;
            if (part == 2) {
                // V transposed: [B,H,D,S]; 4 consecutive s -> ushort4 store
                ushort4 pk;
                unsigned short* p = reinterpret_cast<unsigned short*>(&pk);
#pragma unroll
                for (int r = 0; r < 4; ++r) p[r] = f2bf(acc[mi][ni][r] + bv);
                *reinterpret_cast<ushort4*>(
                    &vo[(((size_t)bb * H_ + h) * D_ + d) * S_ + s0]) = pk;
            } else {
                unsigned short* dst = part == 0 ? qo : ko;
                float scale = part == 0 ? 0.125f : 1.0f;
#pragma unroll
                for (int r = 0; r < 4; ++r) {
                    float vv = (acc[mi][ni][r] + bv) * scale;
                    dst[(((size_t)bb * H_ + h) * S_ + s0 + r) * D_ + d] = f2bf(vv);
                }
            }
        }
    }
}

// ---------- GEMM2: out = z @ w_proj + b_proj (f32 out) ----------
__global__ __launch_bounds__(256) void gemm_proj(const unsigned short* __restrict__ A,
                                                 const unsigned short* __restrict__ Bt,
                                                 const float* __restrict__ bias,
                                                 float* __restrict__ out) {
    __shared__ __align__(16) unsigned short As[128][40];
    __shared__ __align__(16) unsigned short Bs[128][40];
    const int K = 1024;
    int m0 = blockIdx.y << 7, n0 = blockIdx.x << 7;
    int tid = threadIdx.x;
    int w = tid >> 6, l = tid & 63, lg = l >> 4, lr = l & 15;
    int wm = (w >> 1) << 6, wn = (w & 1) << 6;
    f32x4 acc[4][4] = {};
    int ar = tid >> 2, ac = (tid & 3) << 3;

    for (int kt = 0; kt < K; kt += 32) {
        __syncthreads();
#pragma unroll
        for (int it = 0; it < 2; ++it) {
            int r = ar + (it << 6), c = ac;
            *reinterpret_cast<uint4*>(&As[r][c]) =
                *reinterpret_cast<const uint4*>(&A[(size_t)(m0 + r) * K + kt + c]);
            *reinterpret_cast<uint4*>(&Bs[r][c]) =
                *reinterpret_cast<const uint4*>(&Bt[(size_t)(n0 + r) * K + kt + c]);
        }
        __syncthreads();
        bf16x8 af[4], bfr[4];
#pragma unroll
        for (int mi = 0; mi < 4; ++mi)
            af[mi] = *reinterpret_cast<const bf16x8*>(&As[wm + mi * 16 + lr][lg << 3]);
#pragma unroll
        for (int ni = 0; ni < 4; ++ni)
            bfr[ni] = *reinterpret_cast<const bf16x8*>(&Bs[wn + ni * 16 + lr][lg << 3]);
#pragma unroll
        for (int mi = 0; mi < 4; ++mi)
#pragma unroll
            for (int ni = 0; ni < 4; ++ni)
                acc[mi][ni] = __builtin_amdgcn_mfma_f32_16x16x32_bf16(af[mi], bfr[ni], acc[mi][ni], 0, 0, 0);
    }
#pragma unroll
    for (int mi = 0; mi < 4; ++mi) {
#pragma unroll
        for (int ni = 0; ni < 4; ++ni) {
            int col = n0 + wn + ni * 16 + lr;
            float bv = bias[col];
#pragma unroll
            for (int r = 0; r < 4; ++r) {
                int row = m0 + wm + mi * 16 + (lg << 2) + r;
                out[(size_t)row * F_ + col] = acc[mi][ni][r] + bv;
            }
        }
    }
}

// ---------- causal flash attention, no K/V staging (L2-resident), no barriers ----------
// q,k: [B,H,S,D] bf16 (q pre-scaled). vt: [B,H,D,S] bf16. z: [B,S,H*D] bf16
__global__ __launch_bounds__(256) void attn_kernel(const unsigned short* __restrict__ q,
                                                   const unsigned short* __restrict__ k,
                                                   const unsigned short* __restrict__ vt,
                                                   unsigned short* __restrict__ z) {
    // per-wave P re-layout buffer; stride 72 keeps b128 reads 16B-aligned, writes <=4-way
    __shared__ __align__(16) unsigned short Pl[4][16][72];
    int bh = blockIdx.x;
    int qt = gridDim.y - 1 - blockIdx.y;   // longest blocks dispatched first
    int q0 = qt << 6;
    int tid = threadIdx.x, w = tid >> 6, l = tid & 63, lg = l >> 4, lr = l & 15;
    int q0w = q0 + (w << 4);
    size_t base = (size_t)bh * S_ * D_;    // q,k: [S][D]; vt: [D][S] (same byte extent)

    bf16x8 qf[2];
#pragma unroll
    for (int c = 0; c < 2; ++c)
        qf[c] = *reinterpret_cast<const bf16x8*>(&q[base + (size_t)(q0w + lr) * D_ + (lg << 3) + 32 * c]);

    float m[4], lsum[4];
    f32x4 o[4] = {};
#pragma unroll
    for (int r = 0; r < 4; ++r) { m[r] = -1e30f; lsum[r] = 0.f; }

    int ntiles = qt + 1;
    for (int jt = 0; jt < ntiles; ++jt) {
        int j = jt << 6;

        // ---- S = Q K^T (K fragments straight from global; coalesced 2KB/instr, L2-hit) ----
        f32x4 s[4] = {};
#pragma unroll
        for (int nt = 0; nt < 4; ++nt)
#pragma unroll
            for (int c = 0; c < 2; ++c) {
                bf16x8 kf = *reinterpret_cast<const bf16x8*>(
                    &k[base + (size_t)(j + nt * 16 + lr) * D_ + (lg << 3) + 32 * c]);
                s[nt] = __builtin_amdgcn_mfma_f32_16x16x32_bf16(qf[c], kf, s[nt], 0, 0, 0);
            }

        // ---- causal mask + row max ----
        float pm[4];
#pragma unroll
        for (int r = 0; r < 4; ++r) pm[r] = -1e30f;
#pragma unroll
        for (int nt = 0; nt < 4; ++nt) {
            int col = j + nt * 16 + lr;
#pragma unroll
            for (int r = 0; r < 4; ++r) {
                int qrow = q0w + (lg << 2) + r;
                if (col > qrow) s[nt][r] = -1e30f;
                pm[r] = fmaxf(pm[r], s[nt][r]);
            }
        }
#pragma unroll
        for (int off = 1; off < 16; off <<= 1)
#pragma unroll
            for (int r = 0; r < 4; ++r) pm[r] = fmaxf(pm[r], __shfl_xor(pm[r], off));

        // ---- online softmax ----
        float ps[4], scl[4];
#pragma unroll
        for (int r = 0; r < 4; ++r) {
            float mn = fmaxf(m[r], pm[r]);
            scl[r] = __expf(m[r] - mn);
            m[r] = mn;
            ps[r] = 0.f;
        }
#pragma unroll
        for (int nt = 0; nt < 4; ++nt)
#pragma unroll
            for (int r = 0; r < 4; ++r) {
                float p = __expf(s[nt][r] - m[r]);
                ps[r] += p;
                Pl[w][(lg << 2) + r][nt * 16 + lr] = f2bf(p);
            }
#pragma unroll
        for (int off = 1; off < 16; off <<= 1)
#pragma unroll
            for (int r = 0; r < 4; ++r) ps[r] += __shfl_xor(ps[r], off);
#pragma unroll
        for (int r = 0; r < 4; ++r) lsum[r] = lsum[r] * scl[r] + ps[r];
#pragma unroll
        for (int dt = 0; dt < 4; ++dt)
#pragma unroll
            for (int r = 0; r < 4; ++r) o[dt][r] *= scl[r];

        // ---- O += P V  (P via per-wave LDS re-layout; V^T fragments from global) ----
        bf16x8 pa[2];
#pragma unroll
        for (int c = 0; c < 2; ++c)
            pa[c] = *reinterpret_cast<const bf16x8*>(&Pl[w][lr][(lg << 3) + 32 * c]);
#pragma unroll
        for (int dt = 0; dt < 4; ++dt)
#pragma unroll
            for (int c = 0; c < 2; ++c) {
                bf16x8 vf = *reinterpret_cast<const bf16x8*>(
                    &vt[base + (size_t)(dt * 16 + lr) * S_ + j + (lg << 3) + 32 * c]);
                o[dt] = __builtin_amdgcn_mfma_f32_16x16x32_bf16(pa[c], vf, o[dt], 0, 0, 0);
            }
    }

    int b = bh >> 4, h = bh & 15;
#pragma unroll
    for (int dt = 0; dt < 4; ++dt)
#pragma unroll
        for (int r = 0; r < 4; ++r) {
            int qrow = q0w + (lg << 2) + r;
            float val = o[dt][r] / lsum[r];
            z[((size_t)(b * S_ + qrow)) * F_ + h * D_ + dt * 16 + lr] = f2bf(val);
        }
}

extern "C" void kernel_launch(void* const* d_in, const int* in_sizes, int n_in,
                              void* d_out, int out_size, void* d_ws, size_t ws_size,
                              hipStream_t stream) {
    const float* x      = (const float*)d_in[0];
    const float* w_attn = (const float*)d_in[1];
    const float* b_attn = (const float*)d_in[2];
    const float* w_proj = (const float*)d_in[3];
    const float* b_proj = (const float*)d_in[4];
    float* out = (float*)d_out;
    char* ws = (char*)d_ws;

    unsigned short* xb   = (unsigned short*)(ws);              // [4096][1024] bf16, reused as z
    unsigned short* wa_t = (unsigned short*)(ws + 8388608);    // [3072][1024]
    unsigned short* wp_t = (unsigned short*)(ws + 14680064);   // [1024][1024]
    unsigned short* qb   = (unsigned short*)(ws + 16777216);   // [B,H,S,D]
    unsigned short* kb   = (unsigned short*)(ws + 25165824);   // [B,H,S,D]
    unsigned short* vb   = (unsigned short*)(ws + 33554432);   // [B,H,D,S] (transposed)
    unsigned short* zb   = xb;                                 // alias: x consumed by gemm_qkv

    cvt_kernel<<<4096, 256, 0, stream>>>(x, xb, (4096 * 1024) / 4);
    tcvt_kernel<<<dim3(96, 32), dim3(32, 8), 0, stream>>>(w_attn, wa_t, 1024, 3072);
    tcvt_kernel<<<dim3(32, 32), dim3(32, 8), 0, stream>>>(w_proj, wp_t, 1024, 1024);
    gemm_qkv<<<dim3(24, 32), 256, 0, stream>>>(xb, wa_t, b_attn, qb, kb, vb);
    attn_kernel<<<dim3(32, 32), 256, 0, stream>>>(qb, kb, vb, zb);
    gemm_proj<<<dim3(8, 32), 256, 0, stream>>>(zb, wp_t, b_proj, out);
}

// Round 3
// 223.044 us; speedup vs baseline: 1.1649x; 1.0888x over previous
//
#include <hip/hip_runtime.h>

#define B_ 2
#define S_ 2048
#define F_ 1024
#define H_ 16
#define D_ 64

typedef __bf16 bf16x8 __attribute__((ext_vector_type(8)));
typedef float f32x4 __attribute__((ext_vector_type(4)));

__device__ __forceinline__ unsigned short f2bf(float f) {
    union { float f; unsigned int u; } v;
    v.f = f;
    unsigned int r = v.u + 0x7fffu + ((v.u >> 16) & 1u);
    return (unsigned short)(r >> 16);
}

// ---------- f32 -> bf16 elementwise convert (vectorized) ----------
__global__ void cvt_kernel(const float* __restrict__ in, unsigned short* __restrict__ out, int n4) {
    int i = blockIdx.x * blockDim.x + threadIdx.x;
    if (i >= n4) return;
    float4 v = reinterpret_cast<const float4*>(in)[i];
    ushort4 o;
    o.x = f2bf(v.x); o.y = f2bf(v.y); o.z = f2bf(v.z); o.w = f2bf(v.w);
    reinterpret_cast<ushort4*>(out)[i] = o;
}

// ---------- f32 [R][C] -> bf16 [C][R] transpose-convert ----------
__global__ void tcvt_kernel(const float* __restrict__ in, unsigned short* __restrict__ out, int R, int C) {
    __shared__ float t[32][33];
    int r0 = blockIdx.y << 5, c0 = blockIdx.x << 5;
    int tx = threadIdx.x, ty = threadIdx.y;
#pragma unroll
    for (int kk = 0; kk < 4; ++kk)
        t[ty + 8 * kk][tx] = in[(size_t)(r0 + ty + 8 * kk) * C + c0 + tx];
    __syncthreads();
#pragma unroll
    for (int kk = 0; kk < 4; ++kk)
        out[(size_t)(c0 + ty + 8 * kk) * R + r0 + tx] = f2bf(t[tx][ty + 8 * kk]);
}

// ---------- GEMM1: qkv = x @ w_attn + b_attn; q,k -> [B,H,S,D]; v -> [B,H,D,S]; q *= log2e/8 ----------
__global__ __launch_bounds__(256) void gemm_qkv(const unsigned short* __restrict__ A,
                                                const unsigned short* __restrict__ Bt,
                                                const float* __restrict__ bias,
                                                unsigned short* __restrict__ qo,
                                                unsigned short* __restrict__ ko,
                                                unsigned short* __restrict__ vo) {
    __shared__ __align__(16) unsigned short As[128][40];
    __shared__ __align__(16) unsigned short Bs[128][40];
    const int K = 1024;
    int m0 = blockIdx.y << 7, n0 = blockIdx.x << 7;
    int tid = threadIdx.x;
    int w = tid >> 6, l = tid & 63, lg = l >> 4, lr = l & 15;
    int wm = (w >> 1) << 6, wn = (w & 1) << 6;
    f32x4 acc[4][4] = {};
    int ar = tid >> 2, ac = (tid & 3) << 3;

    for (int kt = 0; kt < K; kt += 32) {
        __syncthreads();
#pragma unroll
        for (int it = 0; it < 2; ++it) {
            int r = ar + (it << 6), c = ac;
            *reinterpret_cast<uint4*>(&As[r][c]) =
                *reinterpret_cast<const uint4*>(&A[(size_t)(m0 + r) * K + kt + c]);
            *reinterpret_cast<uint4*>(&Bs[r][c]) =
                *reinterpret_cast<const uint4*>(&Bt[(size_t)(n0 + r) * K + kt + c]);
        }
        __syncthreads();
        bf16x8 af[4], bfr[4];
#pragma unroll
        for (int mi = 0; mi < 4; ++mi)
            af[mi] = *reinterpret_cast<const bf16x8*>(&As[wm + mi * 16 + lr][lg << 3]);
#pragma unroll
        for (int ni = 0; ni < 4; ++ni)
            bfr[ni] = *reinterpret_cast<const bf16x8*>(&Bs[wn + ni * 16 + lr][lg << 3]);
#pragma unroll
        for (int mi = 0; mi < 4; ++mi)
#pragma unroll
            for (int ni = 0; ni < 4; ++ni)
                acc[mi][ni] = __builtin_amdgcn_mfma_f32_16x16x32_bf16(af[mi], bfr[ni], acc[mi][ni], 0, 0, 0);
    }
#pragma unroll
    for (int mi = 0; mi < 4; ++mi) {
#pragma unroll
        for (int ni = 0; ni < 4; ++ni) {
            int col = n0 + wn + ni * 16 + lr;
            float bv = bias[col];
            int part = col >> 10, cc = col & 1023, h = cc >> 6, d = cc & 63;
            int row0 = m0 + wm + mi * 16 + (lg << 2);
            int bb = row0 >> 11, s0 = row0 & 2047;
            if (part == 2) {
                ushort4 pk;
                unsigned short* p = reinterpret_cast<unsigned short*>(&pk);
#pragma unroll
                for (int r = 0; r < 4; ++r) p[r] = f2bf(acc[mi][ni][r] + bv);
                *reinterpret_cast<ushort4*>(
                    &vo[(((size_t)bb * H_ + h) * D_ + d) * S_ + s0]) = pk;
            } else {
                unsigned short* dst = part == 0 ? qo : ko;
                // q pre-scaled by (1/8)*log2(e) so attention exp uses native exp2
                float scale = part == 0 ? 0.125f * 1.44269504f : 1.0f;
#pragma unroll
                for (int r = 0; r < 4; ++r) {
                    float vv = (acc[mi][ni][r] + bv) * scale;
                    dst[(((size_t)bb * H_ + h) * S_ + s0 + r) * D_ + d] = f2bf(vv);
                }
            }
        }
    }
}

// ---------- GEMM2: out = z @ w_proj + b_proj (f32 out) ----------
__global__ __launch_bounds__(256) void gemm_proj(const unsigned short* __restrict__ A,
                                                 const unsigned short* __restrict__ Bt,
                                                 const float* __restrict__ bias,
                                                 float* __restrict__ out) {
    __shared__ __align__(16) unsigned short As[128][40];
    __shared__ __align__(16) unsigned short Bs[128][40];
    const int K = 1024;
    int m0 = blockIdx.y << 7, n0 = blockIdx.x << 7;
    int tid = threadIdx.x;
    int w = tid >> 6, l = tid & 63, lg = l >> 4, lr = l & 15;
    int wm = (w >> 1) << 6, wn = (w & 1) << 6;
    f32x4 acc[4][4] = {};
    int ar = tid >> 2, ac = (tid & 3) << 3;

    for (int kt = 0; kt < K; kt += 32) {
        __syncthreads();
#pragma unroll
        for (int it = 0; it < 2; ++it) {
            int r = ar + (it << 6), c = ac;
            *reinterpret_cast<uint4*>(&As[r][c]) =
                *reinterpret_cast<const uint4*>(&A[(size_t)(m0 + r) * K + kt + c]);
            *reinterpret_cast<uint4*>(&Bs[r][c]) =
                *reinterpret_cast<const uint4*>(&Bt[(size_t)(n0 + r) * K + kt + c]);
        }
        __syncthreads();
        bf16x8 af[4], bfr[4];
#pragma unroll
        for (int mi = 0; mi < 4; ++mi)
            af[mi] = *reinterpret_cast<const bf16x8*>(&As[wm + mi * 16 + lr][lg << 3]);
#pragma unroll
        for (int ni = 0; ni < 4; ++ni)
            bfr[ni] = *reinterpret_cast<const bf16x8*>(&Bs[wn + ni * 16 + lr][lg << 3]);
#pragma unroll
        for (int mi = 0; mi < 4; ++mi)
#pragma unroll
            for (int ni = 0; ni < 4; ++ni)
                acc[mi][ni] = __builtin_amdgcn_mfma_f32_16x16x32_bf16(af[mi], bfr[ni], acc[mi][ni], 0, 0, 0);
    }
#pragma unroll
    for (int mi = 0; mi < 4; ++mi) {
#pragma unroll
        for (int ni = 0; ni < 4; ++ni) {
            int col = n0 + wn + ni * 16 + lr;
            float bv = bias[col];
#pragma unroll
            for (int r = 0; r < 4; ++r) {
                int row = m0 + wm + mi * 16 + (lg << 2) + r;
                out[(size_t)row * F_ + col] = acc[mi][ni][r] + bv;
            }
        }
    }
}

// ---------- attention tile body: V issue-early + K prefetch into knxt ----------
__device__ __forceinline__ void attn_tile(
    const unsigned short* __restrict__ k, const unsigned short* __restrict__ vt,
    size_t base, int j, bool prefetch, bool maskt,
    int lg, int lr, int q0w,
    const bf16x8 (&qf)[2], bf16x8 (&kcur)[8], bf16x8 (&knxt)[8], bf16x8 (&vf)[8],
    float (&m)[4], float (&lsum)[4], f32x4 (&o)[4],
    unsigned short (*Pl)[72])
{
    // issue V loads for THIS tile (used after softmax, ~400cy later)
#pragma unroll
    for (int i = 0; i < 8; ++i) {
        int dt = i >> 1, c = i & 1;
        vf[i] = *reinterpret_cast<const bf16x8*>(
            &vt[base + (size_t)(dt * 16 + lr) * S_ + j + (lg << 3) + 32 * c]);
    }
    // issue K loads for NEXT tile (used next body, ~600cy later)
    if (prefetch) {
        int jn = j + 64;
#pragma unroll
        for (int i = 0; i < 8; ++i) {
            int nt = i >> 1, c = i & 1;
            knxt[i] = *reinterpret_cast<const bf16x8*>(
                &k[base + (size_t)(jn + nt * 16 + lr) * D_ + (lg << 3) + 32 * c]);
        }
    }

    // S = Q K^T from current K register buffer
    f32x4 s[4] = {};
#pragma unroll
    for (int nt = 0; nt < 4; ++nt)
#pragma unroll
        for (int c = 0; c < 2; ++c)
            s[nt] = __builtin_amdgcn_mfma_f32_16x16x32_bf16(qf[c], kcur[nt * 2 + c], s[nt], 0, 0, 0);

    // causal mask: only the diagonal tile needs it
    if (maskt) {
#pragma unroll
        for (int nt = 0; nt < 4; ++nt) {
            int col = j + nt * 16 + lr;
#pragma unroll
            for (int r = 0; r < 4; ++r) {
                int qrow = q0w + (lg << 2) + r;
                if (col > qrow) s[nt][r] = -1e30f;
            }
        }
    }

    float pm[4];
#pragma unroll
    for (int r = 0; r < 4; ++r) pm[r] = -1e30f;
#pragma unroll
    for (int nt = 0; nt < 4; ++nt)
#pragma unroll
        for (int r = 0; r < 4; ++r) pm[r] = fmaxf(pm[r], s[nt][r]);
#pragma unroll
    for (int off = 1; off < 16; off <<= 1)
#pragma unroll
        for (int r = 0; r < 4; ++r) pm[r] = fmaxf(pm[r], __shfl_xor(pm[r], off));

    float ps[4], scl[4];
#pragma unroll
    for (int r = 0; r < 4; ++r) {
        float mn = fmaxf(m[r], pm[r]);
        scl[r] = exp2f(m[r] - mn);   // scores already in log2 domain
        m[r] = mn;
        ps[r] = 0.f;
    }
#pragma unroll
    for (int nt = 0; nt < 4; ++nt)
#pragma unroll
        for (int r = 0; r < 4; ++r) {
            float p = exp2f(s[nt][r] - m[r]);
            ps[r] += p;
            union { float f; unsigned int u; } pu;
            pu.f = p;
            Pl[(lg << 2) + r][nt * 16 + lr] = (unsigned short)((pu.u + 0x8000u) >> 16);
        }
#pragma unroll
    for (int off = 1; off < 16; off <<= 1)
#pragma unroll
        for (int r = 0; r < 4; ++r) ps[r] += __shfl_xor(ps[r], off);
#pragma unroll
    for (int r = 0; r < 4; ++r) lsum[r] = lsum[r] * scl[r] + ps[r];
#pragma unroll
    for (int dt = 0; dt < 4; ++dt)
#pragma unroll
        for (int r = 0; r < 4; ++r) o[dt][r] *= scl[r];

    // O += P V  (P via per-wave LDS re-layout; V from early-issued regs)
    bf16x8 pa[2];
#pragma unroll
    for (int c = 0; c < 2; ++c)
        pa[c] = *reinterpret_cast<const bf16x8*>(&Pl[lr][(lg << 3) + 32 * c]);
#pragma unroll
    for (int dt = 0; dt < 4; ++dt)
#pragma unroll
        for (int c = 0; c < 2; ++c)
            o[dt] = __builtin_amdgcn_mfma_f32_16x16x32_bf16(pa[c], vf[dt * 2 + c], o[dt], 0, 0, 0);
}

// ---------- causal flash attention, register-pipelined, no barriers ----------
__global__ __launch_bounds__(256) void attn_kernel(const unsigned short* __restrict__ q,
                                                   const unsigned short* __restrict__ k,
                                                   const unsigned short* __restrict__ vt,
                                                   unsigned short* __restrict__ z) {
    __shared__ __align__(16) unsigned short Plb[4][16][72];
    int bh = blockIdx.x;
    int qt = gridDim.y - 1 - blockIdx.y;   // longest blocks dispatched first
    int q0 = qt << 6;
    int tid = threadIdx.x, w = tid >> 6, l = tid & 63, lg = l >> 4, lr = l & 15;
    int q0w = q0 + (w << 4);
    size_t base = (size_t)bh * S_ * D_;

    bf16x8 qf[2];
#pragma unroll
    for (int c = 0; c < 2; ++c)
        qf[c] = *reinterpret_cast<const bf16x8*>(&q[base + (size_t)(q0w + lr) * D_ + (lg << 3) + 32 * c]);

    float m[4], lsum[4];
    f32x4 o[4] = {};
#pragma unroll
    for (int r = 0; r < 4; ++r) { m[r] = -1e30f; lsum[r] = 0.f; }

    bf16x8 kA[8], kB[8], vf[8];
    // prologue: K tile 0 into kA
#pragma unroll
    for (int i = 0; i < 8; ++i) {
        int nt = i >> 1, c = i & 1;
        kA[i] = *reinterpret_cast<const bf16x8*>(
            &k[base + (size_t)(nt * 16 + lr) * D_ + (lg << 3) + 32 * c]);
    }

    int ntiles = qt + 1;
    int jt = 0;
    for (;;) {
        attn_tile(k, vt, base, jt << 6, jt + 1 < ntiles, jt == qt, lg, lr, q0w,
                  qf, kA, kB, vf, m, lsum, o, Plb[w]);
        if (++jt >= ntiles) break;
        attn_tile(k, vt, base, jt << 6, jt + 1 < ntiles, jt == qt, lg, lr, q0w,
                  qf, kB, kA, vf, m, lsum, o, Plb[w]);
        if (++jt >= ntiles) break;
    }

    int b = bh >> 4, h = bh & 15;
#pragma unroll
    for (int dt = 0; dt < 4; ++dt)
#pragma unroll
        for (int r = 0; r < 4; ++r) {
            int qrow = q0w + (lg << 2) + r;
            float val = o[dt][r] / lsum[r];
            z[((size_t)(b * S_ + qrow)) * F_ + h * D_ + dt * 16 + lr] = f2bf(val);
        }
}

extern "C" void kernel_launch(void* const* d_in, const int* in_sizes, int n_in,
                              void* d_out, int out_size, void* d_ws, size_t ws_size,
                              hipStream_t stream) {
    const float* x      = (const float*)d_in[0];
    const float* w_attn = (const float*)d_in[1];
    const float* b_attn = (const float*)d_in[2];
    const float* w_proj = (const float*)d_in[3];
    const float* b_proj = (const float*)d_in[4];
    float* out = (float*)d_out;
    char* ws = (char*)d_ws;

    unsigned short* xb   = (unsigned short*)(ws);              // [4096][1024] bf16, reused as z
    unsigned short* wa_t = (unsigned short*)(ws + 8388608);    // [3072][1024]
    unsigned short* wp_t = (unsigned short*)(ws + 14680064);   // [1024][1024]
    unsigned short* qb   = (unsigned short*)(ws + 16777216);   // [B,H,S,D] (pre-scaled by log2e/8)
    unsigned short* kb   = (unsigned short*)(ws + 25165824);   // [B,H,S,D]
    unsigned short* vb   = (unsigned short*)(ws + 33554432);   // [B,H,D,S] (transposed)
    unsigned short* zb   = xb;                                 // alias: x consumed by gemm_qkv

    cvt_kernel<<<4096, 256, 0, stream>>>(x, xb, (4096 * 1024) / 4);
    tcvt_kernel<<<dim3(96, 32), dim3(32, 8), 0, stream>>>(w_attn, wa_t, 1024, 3072);
    tcvt_kernel<<<dim3(32, 32), dim3(32, 8), 0, stream>>>(w_proj, wp_t, 1024, 1024);
    gemm_qkv<<<dim3(24, 32), 256, 0, stream>>>(xb, wa_t, b_attn, qb, kb, vb);
    attn_kernel<<<dim3(32, 32), 256, 0, stream>>>(qb, kb, vb, zb);
    gemm_proj<<<dim3(8, 32), 256, 0, stream>>>(zb, wp_t, b_proj, out);
}

// Round 4
// 167.532 us; speedup vs baseline: 1.5508x; 1.3313x over previous
//
#include <hip/hip_runtime.h>

#define B_ 2
#define S_ 2048
#define F_ 1024
#define H_ 16
#define D_ 64

typedef __bf16 bf16x8 __attribute__((ext_vector_type(8)));
typedef float f32x4 __attribute__((ext_vector_type(4)));
typedef float f32x16 __attribute__((ext_vector_type(16)));

union U8 { unsigned int u[4]; bf16x8 v; };

__device__ __forceinline__ unsigned short f2bf(float f) {
    union { float f; unsigned int u; } v;
    v.f = f;
    unsigned int r = v.u + 0x7fffu + ((v.u >> 16) & 1u);
    return (unsigned short)(r >> 16);
}

__device__ __forceinline__ unsigned int cvtpk_bf16(float lo, float hi) {
    unsigned int r;
    asm("v_cvt_pk_bf16_f32 %0, %1, %2" : "=v"(r) : "v"(lo), "v"(hi));
    return r;
}

// ---------- f32 -> bf16 elementwise convert (vectorized) ----------
__global__ void cvt_kernel(const float* __restrict__ in, unsigned short* __restrict__ out, int n4) {
    int i = blockIdx.x * blockDim.x + threadIdx.x;
    if (i >= n4) return;
    float4 v = reinterpret_cast<const float4*>(in)[i];
    ushort4 o;
    o.x = f2bf(v.x); o.y = f2bf(v.y); o.z = f2bf(v.z); o.w = f2bf(v.w);
    reinterpret_cast<ushort4*>(out)[i] = o;
}

// ---------- f32 [R][C] -> bf16 [C][R] transpose-convert ----------
__global__ void tcvt_kernel(const float* __restrict__ in, unsigned short* __restrict__ out, int R, int C) {
    __shared__ float t[32][33];
    int r0 = blockIdx.y << 5, c0 = blockIdx.x << 5;
    int tx = threadIdx.x, ty = threadIdx.y;
#pragma unroll
    for (int kk = 0; kk < 4; ++kk)
        t[ty + 8 * kk][tx] = in[(size_t)(r0 + ty + 8 * kk) * C + c0 + tx];
    __syncthreads();
#pragma unroll
    for (int kk = 0; kk < 4; ++kk)
        out[(size_t)(c0 + ty + 8 * kk) * R + r0 + tx] = f2bf(t[tx][ty + 8 * kk]);
}

// ---------- GEMM1: qkv = x @ w_attn + b_attn; q,k -> [B,H,S,D]; v -> [B,H,D,S]; q *= log2e/8 ----------
__global__ __launch_bounds__(256) void gemm_qkv(const unsigned short* __restrict__ A,
                                                const unsigned short* __restrict__ Bt,
                                                const float* __restrict__ bias,
                                                unsigned short* __restrict__ qo,
                                                unsigned short* __restrict__ ko,
                                                unsigned short* __restrict__ vo) {
    __shared__ __align__(16) unsigned short As[128][40];
    __shared__ __align__(16) unsigned short Bs[128][40];
    const int K = 1024;
    int m0 = blockIdx.y << 7, n0 = blockIdx.x << 7;
    int tid = threadIdx.x;
    int w = tid >> 6, l = tid & 63, lg = l >> 4, lr = l & 15;
    int wm = (w >> 1) << 6, wn = (w & 1) << 6;
    f32x4 acc[4][4] = {};
    int ar = tid >> 2, ac = (tid & 3) << 3;

    for (int kt = 0; kt < K; kt += 32) {
        __syncthreads();
#pragma unroll
        for (int it = 0; it < 2; ++it) {
            int r = ar + (it << 6), c = ac;
            *reinterpret_cast<uint4*>(&As[r][c]) =
                *reinterpret_cast<const uint4*>(&A[(size_t)(m0 + r) * K + kt + c]);
            *reinterpret_cast<uint4*>(&Bs[r][c]) =
                *reinterpret_cast<const uint4*>(&Bt[(size_t)(n0 + r) * K + kt + c]);
        }
        __syncthreads();
        bf16x8 af[4], bfr[4];
#pragma unroll
        for (int mi = 0; mi < 4; ++mi)
            af[mi] = *reinterpret_cast<const bf16x8*>(&As[wm + mi * 16 + lr][lg << 3]);
#pragma unroll
        for (int ni = 0; ni < 4; ++ni)
            bfr[ni] = *reinterpret_cast<const bf16x8*>(&Bs[wn + ni * 16 + lr][lg << 3]);
#pragma unroll
        for (int mi = 0; mi < 4; ++mi)
#pragma unroll
            for (int ni = 0; ni < 4; ++ni)
                acc[mi][ni] = __builtin_amdgcn_mfma_f32_16x16x32_bf16(af[mi], bfr[ni], acc[mi][ni], 0, 0, 0);
    }
#pragma unroll
    for (int mi = 0; mi < 4; ++mi) {
#pragma unroll
        for (int ni = 0; ni < 4; ++ni) {
            int col = n0 + wn + ni * 16 + lr;
            float bv = bias[col];
            int part = col >> 10, cc = col & 1023, h = cc >> 6, d = cc & 63;
            int row0 = m0 + wm + mi * 16 + (lg << 2);
            int bb = row0 >> 11, s0 = row0 & 2047;
            if (part == 2) {
                ushort4 pk;
                unsigned short* p = reinterpret_cast<unsigned short*>(&pk);
#pragma unroll
                for (int r = 0; r < 4; ++r) p[r] = f2bf(acc[mi][ni][r] + bv);
                *reinterpret_cast<ushort4*>(
                    &vo[(((size_t)bb * H_ + h) * D_ + d) * S_ + s0]) = pk;
            } else {
                unsigned short* dst = part == 0 ? qo : ko;
                // q pre-scaled by (1/8)*log2(e) so attention exp uses native exp2
                float scale = part == 0 ? 0.125f * 1.44269504f : 1.0f;
#pragma unroll
                for (int r = 0; r < 4; ++r) {
                    float vv = (acc[mi][ni][r] + bv) * scale;
                    dst[(((size_t)bb * H_ + h) * S_ + s0 + r) * D_ + d] = f2bf(vv);
                }
            }
        }
    }
}

// ---------- GEMM2: out = z @ w_proj + b_proj (f32 out) ----------
__global__ __launch_bounds__(256) void gemm_proj(const unsigned short* __restrict__ A,
                                                 const unsigned short* __restrict__ Bt,
                                                 const float* __restrict__ bias,
                                                 float* __restrict__ out) {
    __shared__ __align__(16) unsigned short As[128][40];
    __shared__ __align__(16) unsigned short Bs[128][40];
    const int K = 1024;
    int m0 = blockIdx.y << 7, n0 = blockIdx.x << 7;
    int tid = threadIdx.x;
    int w = tid >> 6, l = tid & 63, lg = l >> 4, lr = l & 15;
    int wm = (w >> 1) << 6, wn = (w & 1) << 6;
    f32x4 acc[4][4] = {};
    int ar = tid >> 2, ac = (tid & 3) << 3;

    for (int kt = 0; kt < K; kt += 32) {
        __syncthreads();
#pragma unroll
        for (int it = 0; it < 2; ++it) {
            int r = ar + (it << 6), c = ac;
            *reinterpret_cast<uint4*>(&As[r][c]) =
                *reinterpret_cast<const uint4*>(&A[(size_t)(m0 + r) * K + kt + c]);
            *reinterpret_cast<uint4*>(&Bs[r][c]) =
                *reinterpret_cast<const uint4*>(&Bt[(size_t)(n0 + r) * K + kt + c]);
        }
        __syncthreads();
        bf16x8 af[4], bfr[4];
#pragma unroll
        for (int mi = 0; mi < 4; ++mi)
            af[mi] = *reinterpret_cast<const bf16x8*>(&As[wm + mi * 16 + lr][lg << 3]);
#pragma unroll
        for (int ni = 0; ni < 4; ++ni)
            bfr[ni] = *reinterpret_cast<const bf16x8*>(&Bs[wn + ni * 16 + lr][lg << 3]);
#pragma unroll
        for (int mi = 0; mi < 4; ++mi)
#pragma unroll
            for (int ni = 0; ni < 4; ++ni)
                acc[mi][ni] = __builtin_amdgcn_mfma_f32_16x16x32_bf16(af[mi], bfr[ni], acc[mi][ni], 0, 0, 0);
    }
#pragma unroll
    for (int mi = 0; mi < 4; ++mi) {
#pragma unroll
        for (int ni = 0; ni < 4; ++ni) {
            int col = n0 + wn + ni * 16 + lr;
            float bv = bias[col];
#pragma unroll
            for (int r = 0; r < 4; ++r) {
                int row = m0 + wm + mi * 16 + (lg << 2) + r;
                out[(size_t)row * F_ + col] = acc[mi][ni][r] + bv;
            }
        }
    }
}

// ---------- attention 32x32 tile: swapped QK^T, in-register softmax (T12), O^T accumulate ----------
__device__ __forceinline__ void attn_tile32(
    const unsigned short* __restrict__ k, const unsigned short* __restrict__ vt,
    size_t base, int j, bool pref, bool diag, int qcol, int hi,
    const bf16x8 (&qf)[4], bf16x8 (&kcur)[4], bf16x8 (&knxt)[4],
    float &m, float &lsum, f32x16 &ot0, f32x16 &ot1)
{
    // V^T A-fragments for THIS tile (used after softmax, ~400cy later)
    bf16x8 vf[4];
#pragma unroll
    for (int db = 0; db < 2; ++db)
#pragma unroll
        for (int kf = 0; kf < 2; ++kf)
            vf[db * 2 + kf] = *reinterpret_cast<const bf16x8*>(
                &vt[base + (size_t)(db * 32 + qcol) * S_ + j + kf * 16 + hi * 8]);
    // K A-fragments for NEXT tile
    if (pref) {
#pragma unroll
        for (int kf = 0; kf < 4; ++kf)
            knxt[kf] = *reinterpret_cast<const bf16x8*>(
                &k[base + (size_t)(j + 32 + qcol) * D_ + kf * 16 + hi * 8]);
    }

    // S^T[k][q] = K Q^T : lane owns column q=qcol, 16 k-rows in regs
    f32x16 st = {};
#pragma unroll
    for (int kf = 0; kf < 4; ++kf)
        st = __builtin_amdgcn_mfma_f32_32x32x16_bf16(kcur[kf], qf[kf], st, 0, 0, 0);

    // causal mask: only diagonal tile (j == q0)
    if (diag) {
        int qmh = qcol - 4 * hi;
#pragma unroll
        for (int r = 0; r < 16; ++r) {
            const int kbase = (r & 3) + 8 * (r >> 2);
            st[r] = (kbase > qmh) ? -1e30f : st[r];
        }
    }

    // row max: in-register tree + single cross-half exchange
    float pm = st[0];
#pragma unroll
    for (int r = 1; r < 16; ++r) pm = fmaxf(pm, st[r]);
    pm = fmaxf(pm, __shfl_xor(pm, 32));

    // defer-max (T13): only rescale when max grows beyond threshold (log2 domain)
    if (!__all(pm <= m + 8.0f)) {
        float mn = fmaxf(m, pm);
        float scl = exp2f(m - mn);
        m = mn;
        lsum *= scl;
        ot0 *= scl;
        ot1 *= scl;
    }

    float ps = 0.f;
#pragma unroll
    for (int r = 0; r < 16; ++r) { st[r] = exp2f(st[r] - m); ps += st[r]; }
    ps += __shfl_xor(ps, 32);
    lsum += ps;

    // pack P -> bf16 B-fragments via cvt_pk + permlane32_swap (T12)
    U8 pa0, pa1;
#pragma unroll
    for (int f = 0; f < 2; ++f) {
        unsigned int a0 = cvtpk_bf16(st[f * 8 + 0], st[f * 8 + 1]);
        unsigned int b0 = cvtpk_bf16(st[f * 8 + 4], st[f * 8 + 5]);
        asm("v_permlane32_swap_b32 %0, %1" : "+v"(a0), "+v"(b0));
        unsigned int a1 = cvtpk_bf16(st[f * 8 + 2], st[f * 8 + 3]);
        unsigned int b1 = cvtpk_bf16(st[f * 8 + 6], st[f * 8 + 7]);
        asm("v_permlane32_swap_b32 %0, %1" : "+v"(a1), "+v"(b1));
        U8& pa = f ? pa1 : pa0;
        pa.u[0] = a0; pa.u[1] = a1; pa.u[2] = b0; pa.u[3] = b1;
    }

    // O^T[d][q] += V^T P^T
    ot0 = __builtin_amdgcn_mfma_f32_32x32x16_bf16(vf[0], pa0.v, ot0, 0, 0, 0);
    ot0 = __builtin_amdgcn_mfma_f32_32x32x16_bf16(vf[1], pa1.v, ot0, 0, 0, 0);
    ot1 = __builtin_amdgcn_mfma_f32_32x32x16_bf16(vf[2], pa0.v, ot1, 0, 0, 0);
    ot1 = __builtin_amdgcn_mfma_f32_32x32x16_bf16(vf[3], pa1.v, ot1, 0, 0, 0);
}

// ---------- causal flash attention: 1 wave/block, 32 q-rows/wave, zero LDS, zero barriers ----------
__global__ __launch_bounds__(64, 3) void attn_kernel(const unsigned short* __restrict__ q,
                                                     const unsigned short* __restrict__ k,
                                                     const unsigned short* __restrict__ vt,
                                                     unsigned short* __restrict__ z) {
    int bh = blockIdx.x;
    int qw = gridDim.y - 1 - blockIdx.y;   // longest first
    int q0 = qw << 5;
    int l = threadIdx.x;
    int qcol = l & 31, hi = l >> 5;
    size_t base = (size_t)bh * S_ * D_;

    bf16x8 qf[4];
#pragma unroll
    for (int kf = 0; kf < 4; ++kf)
        qf[kf] = *reinterpret_cast<const bf16x8*>(
            &q[base + (size_t)(q0 + qcol) * D_ + kf * 16 + hi * 8]);

    f32x16 ot0 = {}, ot1 = {};
    float m = -1e30f, lsum = 0.f;

    bf16x8 kA[4], kB[4];
#pragma unroll
    for (int kf = 0; kf < 4; ++kf)
        kA[kf] = *reinterpret_cast<const bf16x8*>(
            &k[base + (size_t)qcol * D_ + kf * 16 + hi * 8]);

    int ntiles = qw + 1;
    int jt = 0;
    for (;;) {
        attn_tile32(k, vt, base, jt << 5, jt + 1 < ntiles, jt == qw, qcol, hi,
                    qf, kA, kB, m, lsum, ot0, ot1);
        if (++jt >= ntiles) break;
        attn_tile32(k, vt, base, jt << 5, jt + 1 < ntiles, jt == qw, qcol, hi,
                    qf, kB, kA, m, lsum, ot0, ot1);
        if (++jt >= ntiles) break;
    }

    float inv = 1.0f / lsum;
    int b = bh >> 4, h = bh & 15;
    size_t zrow = ((size_t)(b * S_ + q0 + qcol)) * F_ + h * D_;
#pragma unroll
    for (int db = 0; db < 2; ++db) {
#pragma unroll
        for (int rq = 0; rq < 4; ++rq) {
            ushort4 pk;
            unsigned short* pp = reinterpret_cast<unsigned short*>(&pk);
#pragma unroll
            for (int i = 0; i < 4; ++i) {
                float val = (db == 0 ? ot0[rq * 4 + i] : ot1[rq * 4 + i]) * inv;
                pp[i] = f2bf(val);
            }
            *reinterpret_cast<ushort4*>(&z[zrow + db * 32 + rq * 8 + hi * 4]) = pk;
        }
    }
}

extern "C" void kernel_launch(void* const* d_in, const int* in_sizes, int n_in,
                              void* d_out, int out_size, void* d_ws, size_t ws_size,
                              hipStream_t stream) {
    const float* x      = (const float*)d_in[0];
    const float* w_attn = (const float*)d_in[1];
    const float* b_attn = (const float*)d_in[2];
    const float* w_proj = (const float*)d_in[3];
    const float* b_proj = (const float*)d_in[4];
    float* out = (float*)d_out;
    char* ws = (char*)d_ws;

    unsigned short* xb   = (unsigned short*)(ws);              // [4096][1024] bf16, reused as z
    unsigned short* wa_t = (unsigned short*)(ws + 8388608);    // [3072][1024]
    unsigned short* wp_t = (unsigned short*)(ws + 14680064);   // [1024][1024]
    unsigned short* qb   = (unsigned short*)(ws + 16777216);   // [B,H,S,D] (pre-scaled by log2e/8)
    unsigned short* kb   = (unsigned short*)(ws + 25165824);   // [B,H,S,D]
    unsigned short* vb   = (unsigned short*)(ws + 33554432);   // [B,H,D,S] (transposed)
    unsigned short* zb   = xb;                                 // alias: x consumed by gemm_qkv

    cvt_kernel<<<4096, 256, 0, stream>>>(x, xb, (4096 * 1024) / 4);
    tcvt_kernel<<<dim3(96, 32), dim3(32, 8), 0, stream>>>(w_attn, wa_t, 1024, 3072);
    tcvt_kernel<<<dim3(32, 32), dim3(32, 8), 0, stream>>>(w_proj, wp_t, 1024, 1024);
    gemm_qkv<<<dim3(24, 32), 256, 0, stream>>>(xb, wa_t, b_attn, qb, kb, vb);
    attn_kernel<<<dim3(32, 64), 64, 0, stream>>>(qb, kb, vb, zb);
    gemm_proj<<<dim3(8, 32), 256, 0, stream>>>(zb, wp_t, b_proj, out);
}